// Round 4
// baseline (309.384 us; speedup 1.0000x reference)
//
#include <hip/hip_runtime.h>
#include <stdint.h>

typedef short short8 __attribute__((ext_vector_type(8)));
typedef float floatx4 __attribute__((ext_vector_type(4)));
typedef float floatx16 __attribute__((ext_vector_type(16)));
typedef unsigned uint4v __attribute__((ext_vector_type(4)));

#define MFMA16(a, b, c) __builtin_amdgcn_mfma_f32_16x16x32_bf16((a), (b), (c), 0, 0, 0)
#define MFMA32(a, b, c) __builtin_amdgcn_mfma_f32_32x32x16_bf16((a), (b), (c), 0, 0, 0)

#define SPLITS 3

__device__ __forceinline__ unsigned short f2bf(float f) {
    union { float f; unsigned u; } v; v.f = f;
    unsigned u = v.u;
    unsigned r = (u + 0x7FFFu + ((u >> 16) & 1u)) >> 16;
    return (unsigned short)r;
}
// fast pack: round-half-up both floats to bf16, pack lo|hi<<16 in one v_perm
__device__ __forceinline__ unsigned pkfast(float lo, float hi) {
    unsigned a = __float_as_uint(lo) + 0x8000u;
    unsigned b = __float_as_uint(hi) + 0x8000u;
    return __builtin_amdgcn_perm(b, a, 0x07060302u);
}

// ---------------------------------------------------------------------------
// prep: convert weights to bf16; pad W_w [256,131] -> [256,160] with zeros
// ---------------------------------------------------------------------------
__global__ void k_prep(const float* th, const float* ph, const float* gw, const float* Ww,
                       unsigned short* TW, unsigned short* PW, unsigned short* GW,
                       unsigned short* Wp) {
    int i = blockIdx.x * 256 + threadIdx.x;
    if (i < 32768) {
        TW[i] = f2bf(th[i]);
    } else if (i < 65536) {
        PW[i - 32768] = f2bf(ph[i - 32768]);
    } else if (i < 98304) {
        GW[i - 65536] = f2bf(gw[i - 65536]);
    } else if (i < 98304 + 256 * 160) {
        int j = i - 98304;
        int oc = j / 160, k = j - oc * 160;
        Wp[j] = (k < 131) ? f2bf(Ww[oc * 131 + k]) : (unsigned short)0;
    }
}

// ---------------------------------------------------------------------------
// pool: xp[n][c][t][hd][wd] = sum_{3x3 window, stride2, pad1}(x)/9
// ---------------------------------------------------------------------------
__global__ void k_pool(const float* __restrict__ x, float* __restrict__ xp) {
    int e = blockIdx.x * 256 + threadIdx.x;           // < 2*256*4096
    int wd = e & 31, hd = (e >> 5) & 31, t = (e >> 10) & 3, c = (e >> 12) & 255, n = e >> 20;
    const float* base = x + (((size_t)(n * 256 + c) * 4 + t) << 12);
    int h0 = 2 * hd - 1, w0 = 2 * wd - 1;
    float s = 0.f;
    #pragma unroll
    for (int dh = 0; dh < 3; ++dh) {
        int h = h0 + dh;
        if ((unsigned)h < 64u) {
            const float* row = base + h * 64;
            #pragma unroll
            for (int dw = 0; dw < 3; ++dw) {
                int w = w0 + dw;
                if ((unsigned)w < 64u) s += row[w];
            }
        }
    }
    xp[((size_t)(n * 256 + c) << 12) + (t << 10) + (hd << 5) + wd] = s * (1.f / 9.f);
}

// ---------------------------------------------------------------------------
// conv_q: Q[n*16384+px][ic] = sum_c x[n][c][px]*theta_w[ic][c] + theta_b[ic]
// Epilogue: C-tile -> per-wave LDS transpose -> coalesced dwordx4 stores.
// ---------------------------------------------------------------------------
__launch_bounds__(256)
__global__ void k_convq(const float* __restrict__ x, const unsigned short* __restrict__ TW,
                        const float* __restrict__ tb, unsigned short* __restrict__ Q) {
    __shared__ unsigned short Qs[4][16][132];   // [wave][px][ic], +4 pad
    int tid = threadIdx.x, wid = tid >> 6, lane = tid & 63, quad = lane >> 4, l16 = lane & 15;
    int n = blockIdx.y;
    int px0 = blockIdx.x * 64 + wid * 16;
    const float* xb = x + ((size_t)n << 22) + px0 + l16;
    floatx4 acc[8];
    #pragma unroll
    for (int i = 0; i < 8; ++i) acc[i] = (floatx4)0.f;
    for (int kc = 0; kc < 8; ++kc) {
        int cbase = kc * 32 + quad * 8;
        uint4v bu;
        #pragma unroll
        for (int j = 0; j < 4; ++j)
            bu[j] = pkfast(xb[(size_t)(cbase + 2 * j) << 14],
                           xb[(size_t)(cbase + 2 * j + 1) << 14]);
        short8 b = __builtin_bit_cast(short8, bu);
        #pragma unroll
        for (int mt = 0; mt < 8; ++mt) {
            short8 a = *(const short8*)(TW + (mt * 16 + l16) * 256 + cbase);
            acc[mt] = MFMA16(a, b, acc[mt]);
        }
    }
    #pragma unroll
    for (int mt = 0; mt < 8; ++mt) {
        int ic = mt * 16 + quad * 4;
        uint2 w;
        w.x = pkfast(acc[mt][0] + tb[ic], acc[mt][1] + tb[ic + 1]);
        w.y = pkfast(acc[mt][2] + tb[ic + 2], acc[mt][3] + tb[ic + 3]);
        *(uint2*)&Qs[wid][l16][ic] = w;
    }
    // same-wave LDS readback (compiler inserts lgkmcnt wait)
    #pragma unroll
    for (int i = 0; i < 4; ++i) {
        int pxl = i * 4 + quad;
        short8 row = *(const short8*)&Qs[wid][pxl][l16 * 8];
        *(short8*)(Q + ((((size_t)n << 14) + px0 + pxl) << 7) + l16 * 8) = row;
    }
}

// ---------------------------------------------------------------------------
// conv_kv: K[n*4096+key][ic] (phi), Vt[n][ic][key] (g; rows 128..130 grid, 131..159=0)
// Both epilogues LDS-transposed for coalesced stores.
// ---------------------------------------------------------------------------
__launch_bounds__(256)
__global__ void k_convkv(const float* __restrict__ xp,
                         const unsigned short* __restrict__ PW, const float* __restrict__ pb,
                         const unsigned short* __restrict__ GW, const float* __restrict__ gb,
                         unsigned short* __restrict__ K, unsigned short* __restrict__ Vt) {
    __shared__ unsigned short Sh[8576];   // K phase: 4 waves x 16x132; V phase: 64x134
    int tid = threadIdx.x, wid = tid >> 6, lane = tid & 63, quad = lane >> 4, l16 = lane & 15;
    int n = blockIdx.y;
    int k0 = blockIdx.x * 64;
    int key = k0 + wid * 16 + l16;
    const float* xb = xp + ((size_t)n << 20) + key;
    floatx4 ka[8], va[8];
    #pragma unroll
    for (int i = 0; i < 8; ++i) { ka[i] = (floatx4)0.f; va[i] = (floatx4)0.f; }
    for (int kc = 0; kc < 8; ++kc) {
        int cbase = kc * 32 + quad * 8;
        uint4v bu;
        #pragma unroll
        for (int j = 0; j < 4; ++j)
            bu[j] = pkfast(xb[(size_t)(cbase + 2 * j) << 12],
                           xb[(size_t)(cbase + 2 * j + 1) << 12]);
        short8 b = __builtin_bit_cast(short8, bu);
        #pragma unroll
        for (int mt = 0; mt < 8; ++mt) {
            short8 ap = *(const short8*)(PW + (mt * 16 + l16) * 256 + cbase);
            ka[mt] = MFMA16(ap, b, ka[mt]);
            short8 ag = *(const short8*)(GW + (mt * 16 + l16) * 256 + cbase);
            va[mt] = MFMA16(ag, b, va[mt]);
        }
    }
    int hd = (key >> 5) & 31, wdd = key & 31;
    float frac = ((hd == 0) ? 2.f : 3.f) * ((wdd == 0) ? 2.f : 3.f) * (1.f / 9.f);

    // --- K epilogue: per-wave transpose, coalesced b128 stores ---
    unsigned short (*Ks)[132] = (unsigned short(*)[132])(Sh + wid * 2112);
    #pragma unroll
    for (int mt = 0; mt < 8; ++mt) {
        int ic = mt * 16 + quad * 4;
        uint2 w;
        w.x = pkfast(ka[mt][0] + pb[ic] * frac, ka[mt][1] + pb[ic + 1] * frac);
        w.y = pkfast(ka[mt][2] + pb[ic + 2] * frac, ka[mt][3] + pb[ic + 3] * frac);
        *(uint2*)&Ks[l16][ic] = w;
    }
    #pragma unroll
    for (int i = 0; i < 4; ++i) {
        int pxl = i * 4 + quad;
        short8 row = *(const short8*)&Ks[pxl][l16 * 8];
        *(short8*)(K + ((((size_t)n << 12) + k0 + wid * 16 + pxl) << 7) + l16 * 8) = row;
    }

    // --- V epilogue: WG-wide [key][ic] tile, store coalesced rows of Vt[ic][key] ---
    __syncthreads();
    unsigned short (*Vs)[134] = (unsigned short(*)[134])Sh;
    #pragma unroll
    for (int mt = 0; mt < 8; ++mt) {
        int ic = mt * 16 + quad * 4;
        uint2 w;
        w.x = pkfast(va[mt][0] + gb[ic] * frac, va[mt][1] + gb[ic + 1] * frac);
        w.y = pkfast(va[mt][2] + gb[ic + 2] * frac, va[mt][3] + gb[ic + 3] * frac);
        *(uint2*)&Vs[wid * 16 + l16][ic] = w;
    }
    __syncthreads();
    #pragma unroll
    for (int it2 = 0; it2 < 4; ++it2) {
        int ic = it2 * 32 + (tid >> 3);
        int kk = (tid & 7) * 8;
        uint4v w;
        #pragma unroll
        for (int j = 0; j < 4; ++j) {
            unsigned s0 = Vs[kk + 2 * j][ic];
            unsigned s1 = Vs[kk + 2 * j + 1][ic];
            w[j] = s0 | (s1 << 16);
        }
        *(uint4v*)(Vt + (((size_t)(n * 160 + ic)) << 12) + k0 + kk) = w;
    }

    // grid channels (128..130) and zero pad rows (131..159): already coalesced
    #pragma unroll
    for (int it = 0; it < 8; ++it) {
        int e = it * 256 + tid;                 // 32 rows x 64 keys
        int row = 128 + (e >> 6);
        int kk = k0 + (e & 63);
        int t = kk >> 10, hh = (kk >> 5) & 31, ww = kk & 31;
        unsigned short v = 0;
        if (row == 128) v = f2bf(((float)t * (1.f / 1.5f) - 1.f) * 0.1f);
        else if (row == 129) v = f2bf((float)hh * (1.f / 15.5f) - 1.f);
        else if (row == 130) v = f2bf((float)ww * (1.f / 7.75f) - 2.f);
        Vt[(((size_t)n * 160 + row) << 12) + kk] = v;
    }
}

// ---------------------------------------------------------------------------
// flash attention v4: 32x32x16 transposed, register-prefetch staging,
// in-register P transpose, split-K=3 (grid 768 = 3 WG/CU), launch_bounds(256,3).
// ---------------------------------------------------------------------------
__launch_bounds__(256, 3)
__global__ void k_attn(const unsigned short* __restrict__ Q, const unsigned short* __restrict__ K,
                       const unsigned short* __restrict__ Vt, unsigned short* __restrict__ Y,
                       float* __restrict__ L) {
    __shared__ short Klds[64][136];   // key x c
    __shared__ short Vlds[160][72];   // vdim x key
    int tid = threadIdx.x, wid = tid >> 6, lane = tid & 63;
    int l32 = lane & 31, half = lane >> 5;
    int n = blockIdx.y, sp = blockIdx.z;
    int c0 = (sp * 64) / SPLITS, c1 = ((sp + 1) * 64) / SPLITS;  // chunk range
    int nch = c1 - c0;
    int q0 = blockIdx.x * 128 + wid * 32;

    const unsigned short* Qr = Q + ((((size_t)n << 14) + q0 + l32) << 7);
    short8 qf[8];
    #pragma unroll
    for (int kc = 0; kc < 8; ++kc) qf[kc] = *(const short8*)(Qr + kc * 16 + half * 8);

    floatx16 O[5];
    #pragma unroll
    for (int t = 0; t < 5; ++t) O[t] = (floatx16)0.f;
    float lacc = 0.f;

    int krow = tid >> 4, kcol = (tid & 15) * 8;      // K: 16 rows/pass x 128 c
    int vrow = tid >> 3, vcol = (tid & 7) * 8;       // V: 32 rows/pass x 64 keys
    const unsigned short* kptr = K + ((((size_t)n << 12) + c0 * 64 + krow) << 7) + kcol;
    const unsigned short* vptr = Vt + ((size_t)(n * 160 + vrow) << 12) + c0 * 64 + vcol;

    short8 kpre[4], vpre[5];
    #pragma unroll
    for (int i = 0; i < 4; ++i) kpre[i] = *(const short8*)(kptr + (size_t)i * 16 * 128);
    #pragma unroll
    for (int i = 0; i < 5; ++i) vpre[i] = *(const short8*)(vptr + ((size_t)i * 32 << 12));

    for (int it = 0; it < nch; ++it) {
        __syncthreads();                      // prior compute done reading LDS
        #pragma unroll
        for (int i = 0; i < 4; ++i) *(short8*)&Klds[i * 16 + krow][kcol] = kpre[i];
        #pragma unroll
        for (int i = 0; i < 5; ++i) *(short8*)&Vlds[i * 32 + vrow][vcol] = vpre[i];
        __syncthreads();
        if (it + 1 < nch) {                   // issue next chunk's loads now
            const unsigned short* kp = kptr + (size_t)(it + 1) * 64 * 128;
            const unsigned short* vp = vptr + (size_t)(it + 1) * 64;
            #pragma unroll
            for (int i = 0; i < 4; ++i) kpre[i] = *(const short8*)(kp + (size_t)i * 16 * 128);
            #pragma unroll
            for (int i = 0; i < 5; ++i) vpre[i] = *(const short8*)(vp + ((size_t)i * 32 << 12));
        }

        #pragma unroll
        for (int ks = 0; ks < 2; ++ks) {      // two 32-key subtiles
            floatx16 st = (floatx16)0.f;
            #pragma unroll
            for (int kc = 0; kc < 8; ++kc) {
                short8 kf = *(const short8*)&Klds[ks * 32 + l32][kc * 16 + half * 8];
                st = MFMA32(kf, qf[kc], st);
            }
            // p = exp(s-12); pack pairs; lane r holds key (r&3)+8*(r>>2)+4*half
            unsigned u[8];
            #pragma unroll
            for (int a = 0; a < 4; ++a) {
                float p0 = exp2f(fmaf(st[4 * a + 0], 1.44269504f, -17.3123404907f));
                float p1 = exp2f(fmaf(st[4 * a + 1], 1.44269504f, -17.3123404907f));
                float p2 = exp2f(fmaf(st[4 * a + 2], 1.44269504f, -17.3123404907f));
                float p3 = exp2f(fmaf(st[4 * a + 3], 1.44269504f, -17.3123404907f));
                lacc += (p0 + p1) + (p2 + p3);
                u[2 * a] = pkfast(p0, p1);
                u[2 * a + 1] = pkfast(p2, p3);
            }
            unsigned xu[8];
            #pragma unroll
            for (int g = 0; g < 8; ++g) xu[g] = (unsigned)__shfl_xor((int)u[g], 32);
            uint4v pw0, pw1;
            pw0[0] = half ? xu[2] : u[0];
            pw0[1] = half ? xu[3] : u[1];
            pw0[2] = half ? u[2] : xu[0];
            pw0[3] = half ? u[3] : xu[1];
            pw1[0] = half ? xu[6] : u[4];
            pw1[1] = half ? xu[7] : u[5];
            pw1[2] = half ? u[6] : xu[4];
            pw1[3] = half ? u[7] : xu[5];
            short8 pf0 = __builtin_bit_cast(short8, pw0);
            short8 pf1 = __builtin_bit_cast(short8, pw1);
            #pragma unroll
            for (int vt = 0; vt < 5; ++vt) {
                short8 vf0 = *(const short8*)&Vlds[vt * 32 + l32][ks * 32 + half * 8];
                O[vt] = MFMA32(vf0, pf0, O[vt]);
                short8 vf1 = *(const short8*)&Vlds[vt * 32 + l32][ks * 32 + 16 + half * 8];
                O[vt] = MFMA32(vf1, pf1, O[vt]);
            }
        }
    }
    // epilogue: raw l (both halves), raw O -> bf16
    float lt = lacc + __shfl_xor(lacc, 32);
    int slab = sp * 2 + n;
    unsigned short* Yb = Y + ((((size_t)slab << 14) + q0 + l32) * 160);
    #pragma unroll
    for (int vt = 0; vt < 5; ++vt)
        #pragma unroll
        for (int g = 0; g < 4; ++g) {
            int vd = vt * 32 + 8 * g + 4 * half;
            uint2 w;
            w.x = pkfast(O[vt][4 * g], O[vt][4 * g + 1]);
            w.y = pkfast(O[vt][4 * g + 2], O[vt][4 * g + 3]);
            *(uint2*)(Yb + vd) = w;
        }
    if (lane < 32) L[(((size_t)slab) << 14) + q0 + lane] = lt;
}

// ---------------------------------------------------------------------------
// final conv + split combine + normalize:
// out[n][oc][p] = (sum_sp sum_k Wp[oc][k]*Y[sp][n][p][k]) / (sum_sp L) + Wb[oc]
// ---------------------------------------------------------------------------
__launch_bounds__(256)
__global__ void k_convf(const unsigned short* __restrict__ Y, const float* __restrict__ L,
                        const unsigned short* __restrict__ Wp, const float* __restrict__ Wb,
                        float* __restrict__ out) {
    int tid = threadIdx.x, wid = tid >> 6, lane = tid & 63, quad = lane >> 4, l16 = lane & 15;
    int n = blockIdx.y;
    int p0 = blockIdx.x * 64;
    floatx4 acc[4][4];
    #pragma unroll
    for (int i = 0; i < 4; ++i)
        #pragma unroll
        for (int j = 0; j < 4; ++j) acc[i][j] = (floatx4)0.f;
    for (int kc = 0; kc < 5; ++kc) {
        int cb = kc * 32 + quad * 8;
        short8 a[4];
        #pragma unroll
        for (int mt = 0; mt < 4; ++mt)
            a[mt] = *(const short8*)(Wp + (size_t)(wid * 64 + mt * 16 + l16) * 160 + cb);
        #pragma unroll
        for (int sp = 0; sp < SPLITS; ++sp) {
            const unsigned short* Yb = Y + ((((size_t)(sp * 2 + n)) << 14) + p0) * 160;
            #pragma unroll
            for (int nt = 0; nt < 4; ++nt) {
                short8 b = *(const short8*)(Yb + (size_t)(nt * 16 + l16) * 160 + cb);
                #pragma unroll
                for (int mt = 0; mt < 4; ++mt) acc[mt][nt] = MFMA16(a[mt], b, acc[mt][nt]);
            }
        }
    }
    float linv[4];
    #pragma unroll
    for (int nt = 0; nt < 4; ++nt) {
        int p = p0 + nt * 16 + l16;
        float ls = 0.f;
        #pragma unroll
        for (int sp = 0; sp < SPLITS; ++sp) ls += L[(((size_t)(sp * 2 + n)) << 14) + p];
        linv[nt] = 1.f / ls;
    }
    #pragma unroll
    for (int mt = 0; mt < 4; ++mt)
        #pragma unroll
        for (int r = 0; r < 4; ++r) {
            int oc = wid * 64 + mt * 16 + quad * 4 + r;
            float bb = Wb[oc];
            float* orow = out + ((((size_t)n << 8) + oc) << 14) + p0;
            #pragma unroll
            for (int nt = 0; nt < 4; ++nt)
                orow[nt * 16 + l16] = acc[mt][nt][r] * linv[nt] + bb;
        }
}

// ---------------------------------------------------------------------------
extern "C" void kernel_launch(void* const* d_in, const int* in_sizes, int n_in,
                              void* d_out, int out_size, void* d_ws, size_t ws_size,
                              hipStream_t stream) {
    (void)in_sizes; (void)n_in; (void)out_size; (void)ws_size;
    const float* x   = (const float*)d_in[0];
    const float* thw = (const float*)d_in[1];
    const float* thb = (const float*)d_in[2];
    const float* phw = (const float*)d_in[3];
    const float* phb = (const float*)d_in[4];
    const float* gw_ = (const float*)d_in[5];
    const float* gb_ = (const float*)d_in[6];
    const float* Ww  = (const float*)d_in[7];
    const float* Wb  = (const float*)d_in[8];
    float* out = (float*)d_out;

    char* ws = (char*)d_ws;
    size_t off = 0;
    auto alloc = [&](size_t b) { size_t o = off; off += (b + 255) & ~(size_t)255; return o; };
    unsigned short* TW = (unsigned short*)(ws + alloc(32768 * 2));
    unsigned short* PW = (unsigned short*)(ws + alloc(32768 * 2));
    unsigned short* GW = (unsigned short*)(ws + alloc(32768 * 2));
    unsigned short* Wp = (unsigned short*)(ws + alloc(40960 * 2));
    unsigned short* Qb = (unsigned short*)(ws + alloc((size_t)32768 * 128 * 2));
    unsigned short* Kb = (unsigned short*)(ws + alloc((size_t)8192 * 128 * 2));
    unsigned short* Vt = (unsigned short*)(ws + alloc((size_t)2 * 160 * 4096 * 2));
    float*          Lb = (float*)(ws + alloc((size_t)SPLITS * 2 * 16384 * 4));
    // Y: [split][n][p][160] = 31.5 MB; xp (8.4 MB) aliases Y's tail (pool/convkv
    // finish before attn writes Y on the same stream).
    size_t ybytes = (size_t)SPLITS * 2 * 16384 * 160 * 2;
    unsigned short* Yb = (unsigned short*)(ws + alloc(ybytes));
    float*          xp = (float*)((char*)Yb + (ybytes - (size_t)2 * 256 * 4096 * 4));

    k_prep<<<(139264 + 255) / 256, 256, 0, stream>>>(thw, phw, gw_, Ww, TW, PW, GW, Wp);
    k_pool<<<8192, 256, 0, stream>>>(x, xp);
    k_convq<<<dim3(256, 2), 256, 0, stream>>>(x, TW, thb, Qb);
    k_convkv<<<dim3(64, 2), 256, 0, stream>>>(xp, PW, phb, GW, gb_, Kb, Vt);
    k_attn<<<dim3(128, 2, SPLITS), 256, 0, stream>>>(Qb, Kb, Vt, Yb, Lb);
    k_convf<<<dim3(256, 2), 256, 0, stream>>>(Yb, Lb, Wp, Wb, out);
}

// Round 5
// 274.847 us; speedup vs baseline: 1.1257x; 1.1257x over previous
//
#include <hip/hip_runtime.h>
#include <stdint.h>

typedef short short8 __attribute__((ext_vector_type(8)));
typedef float floatx4 __attribute__((ext_vector_type(4)));
typedef float floatx16 __attribute__((ext_vector_type(16)));
typedef unsigned uint4v __attribute__((ext_vector_type(4)));

#define MFMA16(a, b, c) __builtin_amdgcn_mfma_f32_16x16x32_bf16((a), (b), (c), 0, 0, 0)
#define MFMA32(a, b, c) __builtin_amdgcn_mfma_f32_32x32x16_bf16((a), (b), (c), 0, 0, 0)

#define SPLITS 2

__device__ __forceinline__ unsigned short f2bf(float f) {
    union { float f; unsigned u; } v; v.f = f;
    unsigned u = v.u;
    unsigned r = (u + 0x7FFFu + ((u >> 16) & 1u)) >> 16;
    return (unsigned short)r;
}
// fast pack: round-half-up both floats to bf16, pack lo|hi<<16 in one v_perm
__device__ __forceinline__ unsigned pkfast(float lo, float hi) {
    unsigned a = __float_as_uint(lo) + 0x8000u;
    unsigned b = __float_as_uint(hi) + 0x8000u;
    return __builtin_amdgcn_perm(b, a, 0x07060302u);
}

// ---------------------------------------------------------------------------
// prep: convert weights to bf16; pad W_w [256,131] -> [256,160] with zeros
// ---------------------------------------------------------------------------
__global__ void k_prep(const float* th, const float* ph, const float* gw, const float* Ww,
                       unsigned short* TW, unsigned short* PW, unsigned short* GW,
                       unsigned short* Wp) {
    int i = blockIdx.x * 256 + threadIdx.x;
    if (i < 32768) {
        TW[i] = f2bf(th[i]);
    } else if (i < 65536) {
        PW[i - 32768] = f2bf(ph[i - 32768]);
    } else if (i < 98304) {
        GW[i - 65536] = f2bf(gw[i - 65536]);
    } else if (i < 98304 + 256 * 160) {
        int j = i - 98304;
        int oc = j / 160, k = j - oc * 160;
        Wp[j] = (k < 131) ? f2bf(Ww[oc * 131 + k]) : (unsigned short)0;
    }
}

// ---------------------------------------------------------------------------
// pool: xp[n][c][t][hd][wd] = sum_{3x3 window, stride2, pad1}(x)/9
// ---------------------------------------------------------------------------
__global__ void k_pool(const float* __restrict__ x, float* __restrict__ xp) {
    int e = blockIdx.x * 256 + threadIdx.x;           // < 2*256*4096
    int wd = e & 31, hd = (e >> 5) & 31, t = (e >> 10) & 3, c = (e >> 12) & 255, n = e >> 20;
    const float* base = x + (((size_t)(n * 256 + c) * 4 + t) << 12);
    int h0 = 2 * hd - 1, w0 = 2 * wd - 1;
    float s = 0.f;
    #pragma unroll
    for (int dh = 0; dh < 3; ++dh) {
        int h = h0 + dh;
        if ((unsigned)h < 64u) {
            const float* row = base + h * 64;
            #pragma unroll
            for (int dw = 0; dw < 3; ++dw) {
                int w = w0 + dw;
                if ((unsigned)w < 64u) s += row[w];
            }
        }
    }
    xp[((size_t)(n * 256 + c) << 12) + (t << 10) + (hd << 5) + wd] = s * (1.f / 9.f);
}

// ---------------------------------------------------------------------------
// conv_q: Q[n*16384+px][ic] = sum_c x[n][c][px]*theta_w[ic][c] + theta_b[ic]
// Epilogue: C-tile -> per-wave LDS transpose -> coalesced dwordx4 stores.
// ---------------------------------------------------------------------------
__launch_bounds__(256)
__global__ void k_convq(const float* __restrict__ x, const unsigned short* __restrict__ TW,
                        const float* __restrict__ tb, unsigned short* __restrict__ Q) {
    __shared__ unsigned short Qs[4][16][132];   // [wave][px][ic], +4 pad
    int tid = threadIdx.x, wid = tid >> 6, lane = tid & 63, quad = lane >> 4, l16 = lane & 15;
    int n = blockIdx.y;
    int px0 = blockIdx.x * 64 + wid * 16;
    const float* xb = x + ((size_t)n << 22) + px0 + l16;
    floatx4 acc[8];
    #pragma unroll
    for (int i = 0; i < 8; ++i) acc[i] = (floatx4)0.f;
    for (int kc = 0; kc < 8; ++kc) {
        int cbase = kc * 32 + quad * 8;
        uint4v bu;
        #pragma unroll
        for (int j = 0; j < 4; ++j)
            bu[j] = pkfast(xb[(size_t)(cbase + 2 * j) << 14],
                           xb[(size_t)(cbase + 2 * j + 1) << 14]);
        short8 b = __builtin_bit_cast(short8, bu);
        #pragma unroll
        for (int mt = 0; mt < 8; ++mt) {
            short8 a = *(const short8*)(TW + (mt * 16 + l16) * 256 + cbase);
            acc[mt] = MFMA16(a, b, acc[mt]);
        }
    }
    #pragma unroll
    for (int mt = 0; mt < 8; ++mt) {
        int ic = mt * 16 + quad * 4;
        uint2 w;
        w.x = pkfast(acc[mt][0] + tb[ic], acc[mt][1] + tb[ic + 1]);
        w.y = pkfast(acc[mt][2] + tb[ic + 2], acc[mt][3] + tb[ic + 3]);
        *(uint2*)&Qs[wid][l16][ic] = w;
    }
    // same-wave LDS readback (compiler inserts lgkmcnt wait)
    #pragma unroll
    for (int i = 0; i < 4; ++i) {
        int pxl = i * 4 + quad;
        short8 row = *(const short8*)&Qs[wid][pxl][l16 * 8];
        *(short8*)(Q + ((((size_t)n << 14) + px0 + pxl) << 7) + l16 * 8) = row;
    }
}

// ---------------------------------------------------------------------------
// conv_kv: K[n*4096+key][ic] (phi), Vt[n][ic][key] (g; rows 128..130 grid, 131..159=0)
// Both epilogues LDS-transposed for coalesced stores.
// ---------------------------------------------------------------------------
__launch_bounds__(256)
__global__ void k_convkv(const float* __restrict__ xp,
                         const unsigned short* __restrict__ PW, const float* __restrict__ pb,
                         const unsigned short* __restrict__ GW, const float* __restrict__ gb,
                         unsigned short* __restrict__ K, unsigned short* __restrict__ Vt) {
    __shared__ unsigned short Sh[8576];   // K phase: 4 waves x 16x132; V phase: 64x134
    int tid = threadIdx.x, wid = tid >> 6, lane = tid & 63, quad = lane >> 4, l16 = lane & 15;
    int n = blockIdx.y;
    int k0 = blockIdx.x * 64;
    int key = k0 + wid * 16 + l16;
    const float* xb = xp + ((size_t)n << 20) + key;
    floatx4 ka[8], va[8];
    #pragma unroll
    for (int i = 0; i < 8; ++i) { ka[i] = (floatx4)0.f; va[i] = (floatx4)0.f; }
    for (int kc = 0; kc < 8; ++kc) {
        int cbase = kc * 32 + quad * 8;
        uint4v bu;
        #pragma unroll
        for (int j = 0; j < 4; ++j)
            bu[j] = pkfast(xb[(size_t)(cbase + 2 * j) << 12],
                           xb[(size_t)(cbase + 2 * j + 1) << 12]);
        short8 b = __builtin_bit_cast(short8, bu);
        #pragma unroll
        for (int mt = 0; mt < 8; ++mt) {
            short8 ap = *(const short8*)(PW + (mt * 16 + l16) * 256 + cbase);
            ka[mt] = MFMA16(ap, b, ka[mt]);
            short8 ag = *(const short8*)(GW + (mt * 16 + l16) * 256 + cbase);
            va[mt] = MFMA16(ag, b, va[mt]);
        }
    }
    int hd = (key >> 5) & 31, wdd = key & 31;
    float frac = ((hd == 0) ? 2.f : 3.f) * ((wdd == 0) ? 2.f : 3.f) * (1.f / 9.f);

    // --- K epilogue: per-wave transpose, coalesced b128 stores ---
    unsigned short (*Ks)[132] = (unsigned short(*)[132])(Sh + wid * 2112);
    #pragma unroll
    for (int mt = 0; mt < 8; ++mt) {
        int ic = mt * 16 + quad * 4;
        uint2 w;
        w.x = pkfast(ka[mt][0] + pb[ic] * frac, ka[mt][1] + pb[ic + 1] * frac);
        w.y = pkfast(ka[mt][2] + pb[ic + 2] * frac, ka[mt][3] + pb[ic + 3] * frac);
        *(uint2*)&Ks[l16][ic] = w;
    }
    #pragma unroll
    for (int i = 0; i < 4; ++i) {
        int pxl = i * 4 + quad;
        short8 row = *(const short8*)&Ks[pxl][l16 * 8];
        *(short8*)(K + ((((size_t)n << 12) + k0 + wid * 16 + pxl) << 7) + l16 * 8) = row;
    }

    // --- V epilogue: WG-wide [key][ic] tile, store coalesced rows of Vt[ic][key] ---
    __syncthreads();
    unsigned short (*Vs)[134] = (unsigned short(*)[134])Sh;
    #pragma unroll
    for (int mt = 0; mt < 8; ++mt) {
        int ic = mt * 16 + quad * 4;
        uint2 w;
        w.x = pkfast(va[mt][0] + gb[ic] * frac, va[mt][1] + gb[ic + 1] * frac);
        w.y = pkfast(va[mt][2] + gb[ic + 2] * frac, va[mt][3] + gb[ic + 3] * frac);
        *(uint2*)&Vs[wid * 16 + l16][ic] = w;
    }
    __syncthreads();
    #pragma unroll
    for (int it2 = 0; it2 < 4; ++it2) {
        int ic = it2 * 32 + (tid >> 3);
        int kk = (tid & 7) * 8;
        uint4v w;
        #pragma unroll
        for (int j = 0; j < 4; ++j) {
            unsigned s0 = Vs[kk + 2 * j][ic];
            unsigned s1 = Vs[kk + 2 * j + 1][ic];
            w[j] = s0 | (s1 << 16);
        }
        *(uint4v*)(Vt + (((size_t)(n * 160 + ic)) << 12) + k0 + kk) = w;
    }

    // grid channels (128..130) and zero pad rows (131..159): already coalesced
    #pragma unroll
    for (int it = 0; it < 8; ++it) {
        int e = it * 256 + tid;                 // 32 rows x 64 keys
        int row = 128 + (e >> 6);
        int kk = k0 + (e & 63);
        int t = kk >> 10, hh = (kk >> 5) & 31, ww = kk & 31;
        unsigned short v = 0;
        if (row == 128) v = f2bf(((float)t * (1.f / 1.5f) - 1.f) * 0.1f);
        else if (row == 129) v = f2bf((float)hh * (1.f / 15.5f) - 1.f);
        else if (row == 130) v = f2bf((float)ww * (1.f / 7.75f) - 2.f);
        Vt[(((size_t)n * 160 + row) << 12) + kk] = v;
    }
}

// ---------------------------------------------------------------------------
// softmax + PV for one 32-key subtile (in-register P transpose)
// ---------------------------------------------------------------------------
__device__ __forceinline__ void softmax_pv(const floatx16 st, int ks,
                                           const short (*Vlds)[72], floatx16* O,
                                           float& lacc, int l32, int half) {
    unsigned u[8];
    #pragma unroll
    for (int a = 0; a < 4; ++a) {
        float p0 = exp2f(fmaf(st[4 * a + 0], 1.44269504f, -17.3123404907f));
        float p1 = exp2f(fmaf(st[4 * a + 1], 1.44269504f, -17.3123404907f));
        float p2 = exp2f(fmaf(st[4 * a + 2], 1.44269504f, -17.3123404907f));
        float p3 = exp2f(fmaf(st[4 * a + 3], 1.44269504f, -17.3123404907f));
        lacc += (p0 + p1) + (p2 + p3);
        u[2 * a] = pkfast(p0, p1);
        u[2 * a + 1] = pkfast(p2, p3);
    }
    unsigned xu[8];
    #pragma unroll
    for (int g = 0; g < 8; ++g) xu[g] = (unsigned)__shfl_xor((int)u[g], 32);
    uint4v pw0, pw1;
    pw0[0] = half ? xu[2] : u[0];
    pw0[1] = half ? xu[3] : u[1];
    pw0[2] = half ? u[2] : xu[0];
    pw0[3] = half ? u[3] : xu[1];
    pw1[0] = half ? xu[6] : u[4];
    pw1[1] = half ? xu[7] : u[5];
    pw1[2] = half ? u[6] : xu[4];
    pw1[3] = half ? u[7] : xu[5];
    short8 pf0 = __builtin_bit_cast(short8, pw0);
    short8 pf1 = __builtin_bit_cast(short8, pw1);
    #pragma unroll
    for (int vt = 0; vt < 5; ++vt) {
        short8 vf0 = *(const short8*)&Vlds[vt * 32 + l32][ks * 32 + half * 8];
        O[vt] = MFMA32(vf0, pf0, O[vt]);
        short8 vf1 = *(const short8*)&Vlds[vt * 32 + l32][ks * 32 + 16 + half * 8];
        O[vt] = MFMA32(vf1, pf1, O[vt]);
    }
}

// ---------------------------------------------------------------------------
// flash attention v5: 32x32x16 transposed, register-prefetch staging,
// in-register P transpose, dual-subtile ILP (two independent QK chains).
// ---------------------------------------------------------------------------
__launch_bounds__(256)
__global__ void k_attn(const unsigned short* __restrict__ Q, const unsigned short* __restrict__ K,
                       const unsigned short* __restrict__ Vt, unsigned short* __restrict__ Y,
                       float* __restrict__ L) {
    __shared__ short Klds[64][136];   // key x c
    __shared__ short Vlds[160][72];   // vdim x key
    int tid = threadIdx.x, wid = tid >> 6, lane = tid & 63;
    int l32 = lane & 31, half = lane >> 5;
    int n = blockIdx.y, sp = blockIdx.z;
    int c0 = (sp * 64) / SPLITS, c1 = ((sp + 1) * 64) / SPLITS;  // chunk range
    int nch = c1 - c0;
    int q0 = blockIdx.x * 128 + wid * 32;

    const unsigned short* Qr = Q + ((((size_t)n << 14) + q0 + l32) << 7);
    short8 qf[8];
    #pragma unroll
    for (int kc = 0; kc < 8; ++kc) qf[kc] = *(const short8*)(Qr + kc * 16 + half * 8);

    floatx16 O[5];
    #pragma unroll
    for (int t = 0; t < 5; ++t) O[t] = (floatx16)0.f;
    float lacc = 0.f;

    int krow = tid >> 4, kcol = (tid & 15) * 8;      // K: 16 rows/pass x 128 c
    int vrow = tid >> 3, vcol = (tid & 7) * 8;       // V: 32 rows/pass x 64 keys
    const unsigned short* kptr = K + ((((size_t)n << 12) + c0 * 64 + krow) << 7) + kcol;
    const unsigned short* vptr = Vt + ((size_t)(n * 160 + vrow) << 12) + c0 * 64 + vcol;

    short8 kpre[4], vpre[5];
    #pragma unroll
    for (int i = 0; i < 4; ++i) kpre[i] = *(const short8*)(kptr + (size_t)i * 16 * 128);
    #pragma unroll
    for (int i = 0; i < 5; ++i) vpre[i] = *(const short8*)(vptr + ((size_t)i * 32 << 12));

    for (int it = 0; it < nch; ++it) {
        __syncthreads();                      // prior compute done reading LDS
        #pragma unroll
        for (int i = 0; i < 4; ++i) *(short8*)&Klds[i * 16 + krow][kcol] = kpre[i];
        #pragma unroll
        for (int i = 0; i < 5; ++i) *(short8*)&Vlds[i * 32 + vrow][vcol] = vpre[i];
        __syncthreads();
        if (it + 1 < nch) {                   // issue next chunk's loads now
            const unsigned short* kp = kptr + (size_t)(it + 1) * 64 * 128;
            const unsigned short* vp = vptr + (size_t)(it + 1) * 64;
            #pragma unroll
            for (int i = 0; i < 4; ++i) kpre[i] = *(const short8*)(kp + (size_t)i * 16 * 128);
            #pragma unroll
            for (int i = 0; i < 5; ++i) vpre[i] = *(const short8*)(vp + ((size_t)i * 32 << 12));
        }

        // QK: two independent 8-MFMA chains (subtile 0 and 1 interleaved)
        floatx16 st0 = (floatx16)0.f, st1 = (floatx16)0.f;
        #pragma unroll
        for (int kc = 0; kc < 8; ++kc) {
            short8 kf0 = *(const short8*)&Klds[l32][kc * 16 + half * 8];
            st0 = MFMA32(kf0, qf[kc], st0);
            short8 kf1 = *(const short8*)&Klds[32 + l32][kc * 16 + half * 8];
            st1 = MFMA32(kf1, qf[kc], st1);
        }
        // softmax+PV subtile 0; its PV MFMAs overlap subtile 1's exp VALU
        softmax_pv(st0, 0, Vlds, O, lacc, l32, half);
        softmax_pv(st1, 1, Vlds, O, lacc, l32, half);
    }
    // epilogue: raw l (both halves), raw O -> bf16
    float lt = lacc + __shfl_xor(lacc, 32);
    int slab = sp * 2 + n;
    unsigned short* Yb = Y + ((((size_t)slab << 14) + q0 + l32) * 160);
    #pragma unroll
    for (int vt = 0; vt < 5; ++vt)
        #pragma unroll
        for (int g = 0; g < 4; ++g) {
            int vd = vt * 32 + 8 * g + 4 * half;
            uint2 w;
            w.x = pkfast(O[vt][4 * g], O[vt][4 * g + 1]);
            w.y = pkfast(O[vt][4 * g + 2], O[vt][4 * g + 3]);
            *(uint2*)(Yb + vd) = w;
        }
    if (lane < 32) L[(((size_t)slab) << 14) + q0 + lane] = lt;
}

// ---------------------------------------------------------------------------
// final conv + split combine + normalize:
// out[n][oc][p] = (sum_sp sum_k Wp[oc][k]*Y[sp][n][p][k]) / (sum_sp L) + Wb[oc]
// ---------------------------------------------------------------------------
__launch_bounds__(256)
__global__ void k_convf(const unsigned short* __restrict__ Y, const float* __restrict__ L,
                        const unsigned short* __restrict__ Wp, const float* __restrict__ Wb,
                        float* __restrict__ out) {
    int tid = threadIdx.x, wid = tid >> 6, lane = tid & 63, quad = lane >> 4, l16 = lane & 15;
    int n = blockIdx.y;
    int p0 = blockIdx.x * 64;
    floatx4 acc[4][4];
    #pragma unroll
    for (int i = 0; i < 4; ++i)
        #pragma unroll
        for (int j = 0; j < 4; ++j) acc[i][j] = (floatx4)0.f;
    for (int kc = 0; kc < 5; ++kc) {
        int cb = kc * 32 + quad * 8;
        short8 a[4];
        #pragma unroll
        for (int mt = 0; mt < 4; ++mt)
            a[mt] = *(const short8*)(Wp + (size_t)(wid * 64 + mt * 16 + l16) * 160 + cb);
        #pragma unroll
        for (int sp = 0; sp < SPLITS; ++sp) {
            const unsigned short* Yb = Y + ((((size_t)(sp * 2 + n)) << 14) + p0) * 160;
            #pragma unroll
            for (int nt = 0; nt < 4; ++nt) {
                short8 b = *(const short8*)(Yb + (size_t)(nt * 16 + l16) * 160 + cb);
                #pragma unroll
                for (int mt = 0; mt < 4; ++mt) acc[mt][nt] = MFMA16(a[mt], b, acc[mt][nt]);
            }
        }
    }
    float linv[4];
    #pragma unroll
    for (int nt = 0; nt < 4; ++nt) {
        int p = p0 + nt * 16 + l16;
        float ls = 0.f;
        #pragma unroll
        for (int sp = 0; sp < SPLITS; ++sp) ls += L[(((size_t)(sp * 2 + n)) << 14) + p];
        linv[nt] = 1.f / ls;
    }
    #pragma unroll
    for (int mt = 0; mt < 4; ++mt)
        #pragma unroll
        for (int r = 0; r < 4; ++r) {
            int oc = wid * 64 + mt * 16 + quad * 4 + r;
            float bb = Wb[oc];
            float* orow = out + ((((size_t)n << 8) + oc) << 14) + p0;
            #pragma unroll
            for (int nt = 0; nt < 4; ++nt)
                orow[nt * 16 + l16] = acc[mt][nt][r] * linv[nt] + bb;
        }
}

// ---------------------------------------------------------------------------
extern "C" void kernel_launch(void* const* d_in, const int* in_sizes, int n_in,
                              void* d_out, int out_size, void* d_ws, size_t ws_size,
                              hipStream_t stream) {
    (void)in_sizes; (void)n_in; (void)out_size; (void)ws_size;
    const float* x   = (const float*)d_in[0];
    const float* thw = (const float*)d_in[1];
    const float* thb = (const float*)d_in[2];
    const float* phw = (const float*)d_in[3];
    const float* phb = (const float*)d_in[4];
    const float* gw_ = (const float*)d_in[5];
    const float* gb_ = (const float*)d_in[6];
    const float* Ww  = (const float*)d_in[7];
    const float* Wb  = (const float*)d_in[8];
    float* out = (float*)d_out;

    char* ws = (char*)d_ws;
    size_t off = 0;
    auto alloc = [&](size_t b) { size_t o = off; off += (b + 255) & ~(size_t)255; return o; };
    unsigned short* TW = (unsigned short*)(ws + alloc(32768 * 2));
    unsigned short* PW = (unsigned short*)(ws + alloc(32768 * 2));
    unsigned short* GW = (unsigned short*)(ws + alloc(32768 * 2));
    unsigned short* Wp = (unsigned short*)(ws + alloc(40960 * 2));
    unsigned short* Qb = (unsigned short*)(ws + alloc((size_t)32768 * 128 * 2));
    unsigned short* Kb = (unsigned short*)(ws + alloc((size_t)8192 * 128 * 2));
    unsigned short* Vt = (unsigned short*)(ws + alloc((size_t)2 * 160 * 4096 * 2));
    float*          Lb = (float*)(ws + alloc((size_t)SPLITS * 2 * 16384 * 4));
    // Y: [split][n][p][160]; xp (8.4 MB) aliases Y's tail (pool/convkv finish
    // before attn writes Y on the same stream; convf reads Y after xp is dead).
    size_t ybytes = (size_t)SPLITS * 2 * 16384 * 160 * 2;
    unsigned short* Yb = (unsigned short*)(ws + alloc(ybytes));
    float*          xp = (float*)((char*)Yb + (ybytes - (size_t)2 * 256 * 4096 * 4));

    k_prep<<<(139264 + 255) / 256, 256, 0, stream>>>(thw, phw, gw_, Ww, TW, PW, GW, Wp);
    k_pool<<<8192, 256, 0, stream>>>(x, xp);
    k_convq<<<dim3(256, 2), 256, 0, stream>>>(x, TW, thb, Qb);
    k_convkv<<<dim3(64, 2), 256, 0, stream>>>(xp, PW, phb, GW, gb_, Kb, Vt);
    k_attn<<<dim3(128, 2, SPLITS), 256, 0, stream>>>(Qb, Kb, Vt, Yb, Lb);
    k_convf<<<dim3(256, 2), 256, 0, stream>>>(Yb, Lb, Wp, Wb, out);
}

// Round 6
// 274.597 us; speedup vs baseline: 1.1267x; 1.0009x over previous
//
#include <hip/hip_runtime.h>
#include <stdint.h>

typedef short short8 __attribute__((ext_vector_type(8)));
typedef float floatx4 __attribute__((ext_vector_type(4)));
typedef float floatx16 __attribute__((ext_vector_type(16)));
typedef unsigned uint4v __attribute__((ext_vector_type(4)));

#define MFMA16(a, b, c) __builtin_amdgcn_mfma_f32_16x16x32_bf16((a), (b), (c), 0, 0, 0)
#define MFMA32(a, b, c) __builtin_amdgcn_mfma_f32_32x32x16_bf16((a), (b), (c), 0, 0, 0)

#define SPLITS 3
// staged chunk image: K 64x136 shorts (17408 B) | V 160x72 shorts (23040 B) | pad 512 B
#define CHUNK_BYTES 40960
#define CHUNK_SHORTS 20480
#define VOFF_SHORTS 8704

typedef __attribute__((address_space(1))) const void* gas1_cp;
typedef __attribute__((address_space(3))) void* las3_p;

__device__ __forceinline__ void gload_lds16(const void* g, void* l) {
    __builtin_amdgcn_global_load_lds((gas1_cp)g, (las3_p)l, 16, 0, 0);
}

__device__ __forceinline__ unsigned short f2bf(float f) {
    union { float f; unsigned u; } v; v.f = f;
    unsigned u = v.u;
    unsigned r = (u + 0x7FFFu + ((u >> 16) & 1u)) >> 16;
    return (unsigned short)r;
}
// fast pack: round-half-up both floats to bf16, pack lo|hi<<16 in one v_perm
__device__ __forceinline__ unsigned pkfast(float lo, float hi) {
    unsigned a = __float_as_uint(lo) + 0x8000u;
    unsigned b = __float_as_uint(hi) + 0x8000u;
    return __builtin_amdgcn_perm(b, a, 0x07060302u);
}

// ---------------------------------------------------------------------------
// prep: convert weights to bf16; pad W_w [256,131] -> [256,160] with zeros
// ---------------------------------------------------------------------------
__global__ void k_prep(const float* th, const float* ph, const float* gw, const float* Ww,
                       unsigned short* TW, unsigned short* PW, unsigned short* GW,
                       unsigned short* Wp) {
    int i = blockIdx.x * 256 + threadIdx.x;
    if (i < 32768) {
        TW[i] = f2bf(th[i]);
    } else if (i < 65536) {
        PW[i - 32768] = f2bf(ph[i - 32768]);
    } else if (i < 98304) {
        GW[i - 65536] = f2bf(gw[i - 65536]);
    } else if (i < 98304 + 256 * 160) {
        int j = i - 98304;
        int oc = j / 160, k = j - oc * 160;
        Wp[j] = (k < 131) ? f2bf(Ww[oc * 131 + k]) : (unsigned short)0;
    }
}

// ---------------------------------------------------------------------------
// pool: xp[n][c][t][hd][wd] = sum_{3x3 window, stride2, pad1}(x)/9
// ---------------------------------------------------------------------------
__global__ void k_pool(const float* __restrict__ x, float* __restrict__ xp) {
    int e = blockIdx.x * 256 + threadIdx.x;           // < 2*256*4096
    int wd = e & 31, hd = (e >> 5) & 31, t = (e >> 10) & 3, c = (e >> 12) & 255, n = e >> 20;
    const float* base = x + (((size_t)(n * 256 + c) * 4 + t) << 12);
    int h0 = 2 * hd - 1, w0 = 2 * wd - 1;
    float s = 0.f;
    #pragma unroll
    for (int dh = 0; dh < 3; ++dh) {
        int h = h0 + dh;
        if ((unsigned)h < 64u) {
            const float* row = base + h * 64;
            #pragma unroll
            for (int dw = 0; dw < 3; ++dw) {
                int w = w0 + dw;
                if ((unsigned)w < 64u) s += row[w];
            }
        }
    }
    xp[((size_t)(n * 256 + c) << 12) + (t << 10) + (hd << 5) + wd] = s * (1.f / 9.f);
}

// ---------------------------------------------------------------------------
// conv_q: Q[n*16384+px][ic] = sum_c x[n][c][px]*theta_w[ic][c] + theta_b[ic]
// Epilogue: C-tile -> per-wave LDS transpose -> coalesced dwordx4 stores.
// ---------------------------------------------------------------------------
__launch_bounds__(256)
__global__ void k_convq(const float* __restrict__ x, const unsigned short* __restrict__ TW,
                        const float* __restrict__ tb, unsigned short* __restrict__ Q) {
    __shared__ unsigned short Qs[4][16][132];   // [wave][px][ic], +4 pad
    int tid = threadIdx.x, wid = tid >> 6, lane = tid & 63, quad = lane >> 4, l16 = lane & 15;
    int n = blockIdx.y;
    int px0 = blockIdx.x * 64 + wid * 16;
    const float* xb = x + ((size_t)n << 22) + px0 + l16;
    floatx4 acc[8];
    #pragma unroll
    for (int i = 0; i < 8; ++i) acc[i] = (floatx4)0.f;
    for (int kc = 0; kc < 8; ++kc) {
        int cbase = kc * 32 + quad * 8;
        uint4v bu;
        #pragma unroll
        for (int j = 0; j < 4; ++j)
            bu[j] = pkfast(xb[(size_t)(cbase + 2 * j) << 14],
                           xb[(size_t)(cbase + 2 * j + 1) << 14]);
        short8 b = __builtin_bit_cast(short8, bu);
        #pragma unroll
        for (int mt = 0; mt < 8; ++mt) {
            short8 a = *(const short8*)(TW + (mt * 16 + l16) * 256 + cbase);
            acc[mt] = MFMA16(a, b, acc[mt]);
        }
    }
    #pragma unroll
    for (int mt = 0; mt < 8; ++mt) {
        int ic = mt * 16 + quad * 4;
        uint2 w;
        w.x = pkfast(acc[mt][0] + tb[ic], acc[mt][1] + tb[ic + 1]);
        w.y = pkfast(acc[mt][2] + tb[ic + 2], acc[mt][3] + tb[ic + 3]);
        *(uint2*)&Qs[wid][l16][ic] = w;
    }
    // same-wave LDS readback (compiler inserts lgkmcnt wait)
    #pragma unroll
    for (int i = 0; i < 4; ++i) {
        int pxl = i * 4 + quad;
        short8 row = *(const short8*)&Qs[wid][pxl][l16 * 8];
        *(short8*)(Q + ((((size_t)n << 14) + px0 + pxl) << 7) + l16 * 8) = row;
    }
}

// ---------------------------------------------------------------------------
// conv_kv: writes staged chunk images for k_attn's global_load_lds:
//   Stg[n][chunk] = [K 64x136 | V 160x72 | pad]  (pads never read)
//   K rows: phi conv + phi_b*frac; V rows 0..127 g conv + g_b*frac,
//   128..130 grid, 131..159 zero.
// ---------------------------------------------------------------------------
__launch_bounds__(256)
__global__ void k_convkv(const float* __restrict__ xp,
                         const unsigned short* __restrict__ PW, const float* __restrict__ pb,
                         const unsigned short* __restrict__ GW, const float* __restrict__ gb,
                         unsigned short* __restrict__ Stg) {
    __shared__ unsigned short Sh[8576];   // K phase: 4 waves x 16x132; V phase: 64x134
    int tid = threadIdx.x, wid = tid >> 6, lane = tid & 63, quad = lane >> 4, l16 = lane & 15;
    int n = blockIdx.y;
    int chunk = blockIdx.x;
    int k0 = chunk * 64;
    int key = k0 + wid * 16 + l16;
    unsigned short* sc = Stg + (size_t)(n * 64 + chunk) * CHUNK_SHORTS;
    const float* xb = xp + ((size_t)n << 20) + key;
    floatx4 ka[8], va[8];
    #pragma unroll
    for (int i = 0; i < 8; ++i) { ka[i] = (floatx4)0.f; va[i] = (floatx4)0.f; }
    for (int kc = 0; kc < 8; ++kc) {
        int cbase = kc * 32 + quad * 8;
        uint4v bu;
        #pragma unroll
        for (int j = 0; j < 4; ++j)
            bu[j] = pkfast(xb[(size_t)(cbase + 2 * j) << 12],
                           xb[(size_t)(cbase + 2 * j + 1) << 12]);
        short8 b = __builtin_bit_cast(short8, bu);
        #pragma unroll
        for (int mt = 0; mt < 8; ++mt) {
            short8 ap = *(const short8*)(PW + (mt * 16 + l16) * 256 + cbase);
            ka[mt] = MFMA16(ap, b, ka[mt]);
            short8 ag = *(const short8*)(GW + (mt * 16 + l16) * 256 + cbase);
            va[mt] = MFMA16(ag, b, va[mt]);
        }
    }
    int hd = (key >> 5) & 31, wdd = key & 31;
    float frac = ((hd == 0) ? 2.f : 3.f) * ((wdd == 0) ? 2.f : 3.f) * (1.f / 9.f);

    // --- K epilogue: per-wave transpose, coalesced b128 stores, stride 136 ---
    unsigned short (*Ks)[132] = (unsigned short(*)[132])(Sh + wid * 2112);
    #pragma unroll
    for (int mt = 0; mt < 8; ++mt) {
        int ic = mt * 16 + quad * 4;
        uint2 w;
        w.x = pkfast(ka[mt][0] + pb[ic] * frac, ka[mt][1] + pb[ic + 1] * frac);
        w.y = pkfast(ka[mt][2] + pb[ic + 2] * frac, ka[mt][3] + pb[ic + 3] * frac);
        *(uint2*)&Ks[l16][ic] = w;
    }
    #pragma unroll
    for (int i = 0; i < 4; ++i) {
        int pxl = i * 4 + quad;
        short8 row = *(const short8*)&Ks[pxl][l16 * 8];
        *(short8*)(sc + (wid * 16 + pxl) * 136 + l16 * 8) = row;
    }

    // --- V epilogue: WG-wide [key][ic] tile -> V image rows, stride 72 ---
    __syncthreads();
    unsigned short (*Vs)[134] = (unsigned short(*)[134])Sh;
    #pragma unroll
    for (int mt = 0; mt < 8; ++mt) {
        int ic = mt * 16 + quad * 4;
        uint2 w;
        w.x = pkfast(va[mt][0] + gb[ic] * frac, va[mt][1] + gb[ic + 1] * frac);
        w.y = pkfast(va[mt][2] + gb[ic + 2] * frac, va[mt][3] + gb[ic + 3] * frac);
        *(uint2*)&Vs[wid * 16 + l16][ic] = w;
    }
    __syncthreads();
    #pragma unroll
    for (int it2 = 0; it2 < 4; ++it2) {
        int ic = it2 * 32 + (tid >> 3);
        int kk = (tid & 7) * 8;
        uint4v w;
        #pragma unroll
        for (int j = 0; j < 4; ++j) {
            unsigned s0 = Vs[kk + 2 * j][ic];
            unsigned s1 = Vs[kk + 2 * j + 1][ic];
            w[j] = s0 | (s1 << 16);
        }
        *(uint4v*)(sc + VOFF_SHORTS + ic * 72 + kk) = w;
    }

    // grid channels (128..130) and zero rows (131..159)
    #pragma unroll
    for (int it = 0; it < 8; ++it) {
        int e = it * 256 + tid;                 // 32 rows x 64 keys
        int row = 128 + (e >> 6);
        int kl = e & 63;
        int kk = k0 + kl;
        int t = kk >> 10, hh = (kk >> 5) & 31, ww = kk & 31;
        unsigned short v = 0;
        if (row == 128) v = f2bf(((float)t * (1.f / 1.5f) - 1.f) * 0.1f);
        else if (row == 129) v = f2bf((float)hh * (1.f / 15.5f) - 1.f);
        else if (row == 130) v = f2bf((float)ww * (1.f / 7.75f) - 2.f);
        sc[VOFF_SHORTS + row * 72 + kl] = v;
    }
}

// ---------------------------------------------------------------------------
// softmax + PV for one 32-key subtile (in-register P transpose)
// ---------------------------------------------------------------------------
__device__ __forceinline__ void softmax_pv(const floatx16 st, int ks,
                                           const short (*Vlds)[72], floatx16* O,
                                           float& lacc, int l32, int half) {
    unsigned u[8];
    #pragma unroll
    for (int a = 0; a < 4; ++a) {
        float p0 = exp2f(fmaf(st[4 * a + 0], 1.44269504f, -17.3123404907f));
        float p1 = exp2f(fmaf(st[4 * a + 1], 1.44269504f, -17.3123404907f));
        float p2 = exp2f(fmaf(st[4 * a + 2], 1.44269504f, -17.3123404907f));
        float p3 = exp2f(fmaf(st[4 * a + 3], 1.44269504f, -17.3123404907f));
        lacc += (p0 + p1) + (p2 + p3);
        u[2 * a] = pkfast(p0, p1);
        u[2 * a + 1] = pkfast(p2, p3);
    }
    unsigned xu[8];
    #pragma unroll
    for (int g = 0; g < 8; ++g) xu[g] = (unsigned)__shfl_xor((int)u[g], 32);
    uint4v pw0, pw1;
    pw0[0] = half ? xu[2] : u[0];
    pw0[1] = half ? xu[3] : u[1];
    pw0[2] = half ? u[2] : xu[0];
    pw0[3] = half ? u[3] : xu[1];
    pw1[0] = half ? xu[6] : u[4];
    pw1[1] = half ? xu[7] : u[5];
    pw1[2] = half ? u[6] : xu[4];
    pw1[3] = half ? u[7] : xu[5];
    short8 pf0 = __builtin_bit_cast(short8, pw0);
    short8 pf1 = __builtin_bit_cast(short8, pw1);
    #pragma unroll
    for (int vt = 0; vt < 5; ++vt) {
        short8 vf0 = *(const short8*)&Vlds[vt * 32 + l32][ks * 32 + half * 8];
        O[vt] = MFMA32(vf0, pf0, O[vt]);
        short8 vf1 = *(const short8*)&Vlds[vt * 32 + l32][ks * 32 + 16 + half * 8];
        O[vt] = MFMA32(vf1, pf1, O[vt]);
    }
}

// ---------------------------------------------------------------------------
// flash attention v6: global_load_lds staging (no staging VGPRs), split-K=3,
// 3 WGs/CU (launch_bounds(256,3)), in-register P transpose.
// ---------------------------------------------------------------------------
__launch_bounds__(256, 3)
__global__ void k_attn(const unsigned short* __restrict__ Q,
                       const unsigned char* __restrict__ Stg,
                       unsigned short* __restrict__ Y, float* __restrict__ L) {
    __shared__ __align__(16) char Sh[CHUNK_BYTES];
    int tid = threadIdx.x, wid = tid >> 6, lane = tid & 63;
    int l32 = lane & 31, half = lane >> 5;
    int n = blockIdx.y, sp = blockIdx.z;
    int c0 = (sp * 64) / SPLITS, c1 = ((sp + 1) * 64) / SPLITS;  // chunk range
    int nch = c1 - c0;
    int q0 = blockIdx.x * 128 + wid * 32;

    const unsigned short* Qr = Q + ((((size_t)n << 14) + q0 + l32) << 7);
    short8 qf[8];
    #pragma unroll
    for (int kc = 0; kc < 8; ++kc) qf[kc] = *(const short8*)(Qr + kc * 16 + half * 8);

    floatx16 O[5];
    #pragma unroll
    for (int t = 0; t < 5; ++t) O[t] = (floatx16)0.f;
    float lacc = 0.f;

    const short (*Klds)[136] = (const short(*)[136])Sh;
    const short (*Vlds)[72] = (const short(*)[72])(Sh + 17408);

    // wave-sliced DMA: wave w copies slices w*10..w*10+9 (1 KB each)
    const unsigned char* gsl = Stg + ((size_t)(n * 64 + c0)) * CHUNK_BYTES
                               + (wid * 10) * 1024 + lane * 16;
    char* lsl = Sh + (wid * 10) * 1024;

    for (int it = 0; it < nch; ++it) {
        __syncthreads();                      // all waves done reading prev chunk
        const unsigned char* g = gsl + (size_t)it * CHUNK_BYTES;
        #pragma unroll
        for (int i = 0; i < 10; ++i)
            gload_lds16(g + i * 1024, lsl + i * 1024);
        asm volatile("s_waitcnt vmcnt(0)" ::: "memory");
        __syncthreads();                      // chunk resident in LDS

        #pragma unroll
        for (int ks = 0; ks < 2; ++ks) {      // two 32-key subtiles
            floatx16 st = (floatx16)0.f;
            #pragma unroll
            for (int kc = 0; kc < 8; ++kc) {
                short8 kf = *(const short8*)&Klds[ks * 32 + l32][kc * 16 + half * 8];
                st = MFMA32(kf, qf[kc], st);
            }
            softmax_pv(st, ks, Vlds, O, lacc, l32, half);
        }
    }
    // epilogue: raw l (both halves), raw O -> bf16
    float lt = lacc + __shfl_xor(lacc, 32);
    int slab = sp * 2 + n;
    unsigned short* Yb = Y + ((((size_t)slab << 14) + q0 + l32) * 160);
    #pragma unroll
    for (int vt = 0; vt < 5; ++vt)
        #pragma unroll
        for (int g = 0; g < 4; ++g) {
            int vd = vt * 32 + 8 * g + 4 * half;
            uint2 w;
            w.x = pkfast(O[vt][4 * g], O[vt][4 * g + 1]);
            w.y = pkfast(O[vt][4 * g + 2], O[vt][4 * g + 3]);
            *(uint2*)(Yb + vd) = w;
        }
    if (lane < 32) L[(((size_t)slab) << 14) + q0 + lane] = lt;
}

// ---------------------------------------------------------------------------
// final conv + split combine + normalize:
// out[n][oc][p] = (sum_sp sum_k Wp[oc][k]*Y[sp][n][p][k]) / (sum_sp L) + Wb[oc]
// ---------------------------------------------------------------------------
__launch_bounds__(256)
__global__ void k_convf(const unsigned short* __restrict__ Y, const float* __restrict__ L,
                        const unsigned short* __restrict__ Wp, const float* __restrict__ Wb,
                        float* __restrict__ out) {
    int tid = threadIdx.x, wid = tid >> 6, lane = tid & 63, quad = lane >> 4, l16 = lane & 15;
    int n = blockIdx.y;
    int p0 = blockIdx.x * 64;
    floatx4 acc[4][4];
    #pragma unroll
    for (int i = 0; i < 4; ++i)
        #pragma unroll
        for (int j = 0; j < 4; ++j) acc[i][j] = (floatx4)0.f;
    for (int kc = 0; kc < 5; ++kc) {
        int cb = kc * 32 + quad * 8;
        short8 a[4];
        #pragma unroll
        for (int mt = 0; mt < 4; ++mt)
            a[mt] = *(const short8*)(Wp + (size_t)(wid * 64 + mt * 16 + l16) * 160 + cb);
        #pragma unroll
        for (int sp = 0; sp < SPLITS; ++sp) {
            const unsigned short* Yb = Y + ((((size_t)(sp * 2 + n)) << 14) + p0) * 160;
            #pragma unroll
            for (int nt = 0; nt < 4; ++nt) {
                short8 b = *(const short8*)(Yb + (size_t)(nt * 16 + l16) * 160 + cb);
                #pragma unroll
                for (int mt = 0; mt < 4; ++mt) acc[mt][nt] = MFMA16(a[mt], b, acc[mt][nt]);
            }
        }
    }
    float linv[4];
    #pragma unroll
    for (int nt = 0; nt < 4; ++nt) {
        int p = p0 + nt * 16 + l16;
        float ls = 0.f;
        #pragma unroll
        for (int sp = 0; sp < SPLITS; ++sp) ls += L[(((size_t)(sp * 2 + n)) << 14) + p];
        linv[nt] = 1.f / ls;
    }
    #pragma unroll
    for (int mt = 0; mt < 4; ++mt)
        #pragma unroll
        for (int r = 0; r < 4; ++r) {
            int oc = wid * 64 + mt * 16 + quad * 4 + r;
            float bb = Wb[oc];
            float* orow = out + ((((size_t)n << 8) + oc) << 14) + p0;
            #pragma unroll
            for (int nt = 0; nt < 4; ++nt)
                orow[nt * 16 + l16] = acc[mt][nt][r] * linv[nt] + bb;
        }
}

// ---------------------------------------------------------------------------
extern "C" void kernel_launch(void* const* d_in, const int* in_sizes, int n_in,
                              void* d_out, int out_size, void* d_ws, size_t ws_size,
                              hipStream_t stream) {
    (void)in_sizes; (void)n_in; (void)out_size; (void)ws_size;
    const float* x   = (const float*)d_in[0];
    const float* thw = (const float*)d_in[1];
    const float* thb = (const float*)d_in[2];
    const float* phw = (const float*)d_in[3];
    const float* phb = (const float*)d_in[4];
    const float* gw_ = (const float*)d_in[5];
    const float* gb_ = (const float*)d_in[6];
    const float* Ww  = (const float*)d_in[7];
    const float* Wb  = (const float*)d_in[8];
    float* out = (float*)d_out;

    char* ws = (char*)d_ws;
    size_t off = 0;
    auto alloc = [&](size_t b) { size_t o = off; off += (b + 255) & ~(size_t)255; return o; };
    unsigned short* TW = (unsigned short*)(ws + alloc(32768 * 2));
    unsigned short* PW = (unsigned short*)(ws + alloc(32768 * 2));
    unsigned short* GW = (unsigned short*)(ws + alloc(32768 * 2));
    unsigned short* Wp = (unsigned short*)(ws + alloc(40960 * 2));
    unsigned short* Qb = (unsigned short*)(ws + alloc((size_t)32768 * 128 * 2));
    unsigned short* St = (unsigned short*)(ws + alloc((size_t)2 * 64 * CHUNK_BYTES));
    float*          Lb = (float*)(ws + alloc((size_t)SPLITS * 2 * 16384 * 4));
    // Y: [split*2+n][p][160]; xp (8.4 MB) aliases Y's tail (pool/convkv finish
    // before attn writes Y on the same stream; convf reads Y after xp is dead).
    size_t ybytes = (size_t)SPLITS * 2 * 16384 * 160 * 2;
    unsigned short* Yb = (unsigned short*)(ws + alloc(ybytes));
    float*          xp = (float*)((char*)Yb + (ybytes - (size_t)2 * 256 * 4096 * 4));

    k_prep<<<(139264 + 255) / 256, 256, 0, stream>>>(thw, phw, gw_, Ww, TW, PW, GW, Wp);
    k_pool<<<8192, 256, 0, stream>>>(x, xp);
    k_convq<<<dim3(256, 2), 256, 0, stream>>>(x, TW, thb, Qb);
    k_convkv<<<dim3(64, 2), 256, 0, stream>>>(xp, PW, phb, GW, gb_, St);
    k_attn<<<dim3(128, 2, SPLITS), 256, 0, stream>>>(Qb, (const unsigned char*)St, Yb, Lb);
    k_convf<<<dim3(256, 2), 256, 0, stream>>>(Yb, Lb, Wp, Wb, out);
}

// Round 7
// 255.223 us; speedup vs baseline: 1.2122x; 1.0759x over previous
//
#include <hip/hip_runtime.h>
#include <stdint.h>

typedef short short8 __attribute__((ext_vector_type(8)));
typedef float floatx4 __attribute__((ext_vector_type(4)));
typedef float floatx16 __attribute__((ext_vector_type(16)));
typedef unsigned uint4v __attribute__((ext_vector_type(4)));

#define MFMA16(a, b, c) __builtin_amdgcn_mfma_f32_16x16x32_bf16((a), (b), (c), 0, 0, 0)
#define MFMA32(a, b, c) __builtin_amdgcn_mfma_f32_32x32x16_bf16((a), (b), (c), 0, 0, 0)

#define SPLITS 3
// staged chunk image: K 64x136 shorts (17408 B) | V 160x72 shorts (23040 B) | pad 512 B
#define CHUNK_BYTES 40960
#define CHUNK_SHORTS 20480
#define VOFF_SHORTS 8704

typedef __attribute__((address_space(1))) const void* gas1_cp;
typedef __attribute__((address_space(3))) void* las3_p;

__device__ __forceinline__ void gload_lds16(const void* g, void* l) {
    __builtin_amdgcn_global_load_lds((gas1_cp)g, (las3_p)l, 16, 0, 0);
}

__device__ __forceinline__ unsigned short f2bf(float f) {
    union { float f; unsigned u; } v; v.f = f;
    unsigned u = v.u;
    unsigned r = (u + 0x7FFFu + ((u >> 16) & 1u)) >> 16;
    return (unsigned short)r;
}
// round-half-up single float -> bf16 (bit-identical to pkfast halves)
__device__ __forceinline__ unsigned short us(float f) {
    return (unsigned short)((__float_as_uint(f) + 0x8000u) >> 16);
}
// fast pack: round-half-up both floats to bf16, pack lo|hi<<16 in one v_perm
__device__ __forceinline__ unsigned pkfast(float lo, float hi) {
    unsigned a = __float_as_uint(lo) + 0x8000u;
    unsigned b = __float_as_uint(hi) + 0x8000u;
    return __builtin_amdgcn_perm(b, a, 0x07060302u);
}

// ---------------------------------------------------------------------------
// prep: convert weights to bf16; pad W_w [256,131] -> [256,160] with zeros
// ---------------------------------------------------------------------------
__global__ void k_prep(const float* th, const float* ph, const float* gw, const float* Ww,
                       unsigned short* TW, unsigned short* PW, unsigned short* GW,
                       unsigned short* Wp) {
    int i = blockIdx.x * 256 + threadIdx.x;
    if (i < 32768) {
        TW[i] = f2bf(th[i]);
    } else if (i < 65536) {
        PW[i - 32768] = f2bf(ph[i - 32768]);
    } else if (i < 98304) {
        GW[i - 65536] = f2bf(gw[i - 65536]);
    } else if (i < 98304 + 256 * 160) {
        int j = i - 98304;
        int oc = j / 160, k = j - oc * 160;
        Wp[j] = (k < 131) ? f2bf(Ww[oc * 131 + k]) : (unsigned short)0;
    }
}

// ---------------------------------------------------------------------------
// xt: transpose x [n][c][px] fp32 -> xT [n][px][c] bf16 (coalesced both sides)
// tile: 64 px x 32 c per WG
// ---------------------------------------------------------------------------
__launch_bounds__(256)
__global__ void k_xt(const float* __restrict__ x, unsigned short* __restrict__ xT) {
    __shared__ unsigned short Xs[64][40];   // [px][c], stride 40 -> 16B-aligned rows
    int tid = threadIdx.x;
    int n = blockIdx.y;
    int px0 = (blockIdx.x & 255) * 64;
    int c0 = (blockIdx.x >> 8) * 32;
    #pragma unroll
    for (int p = 0; p < 2; ++p) {
        int c = c0 + p * 16 + (tid >> 4);
        int l = tid & 15;
        const float* src = x + (((size_t)(n * 256 + c)) << 14) + px0 + 4 * l;
        float4 v = *(const float4*)src;
        int cc = c - c0;
        Xs[4 * l + 0][cc] = us(v.x);
        Xs[4 * l + 1][cc] = us(v.y);
        Xs[4 * l + 2][cc] = us(v.z);
        Xs[4 * l + 3][cc] = us(v.w);
    }
    __syncthreads();
    int px = tid >> 2, c8 = (tid & 3) * 8;
    short8 row = *(const short8*)&Xs[px][c8];
    *(short8*)(xT + (((size_t)n << 14) + px0 + px) * 256 + c0 + c8) = row;
}

// ---------------------------------------------------------------------------
// poolT: 3x3/stride2/pad1 avgpool of x, output TRANSPOSED bf16 xpT[n][key][c]
// tile: 32 keys (one hd row) x 32 c per WG
// ---------------------------------------------------------------------------
__launch_bounds__(256)
__global__ void k_poolT(const float* __restrict__ x, unsigned short* __restrict__ xpT) {
    __shared__ unsigned short P[32][40];    // [wd][c]
    int tid = threadIdx.x;
    int n = blockIdx.y;
    int r = blockIdx.x & 127;               // t = r>>5, hd = r&31
    int c0 = (blockIdx.x >> 7) * 32;
    int t = r >> 5, hd = r & 31;
    int wd = tid & 31;
    int cg = (tid >> 5) * 4;
    int h0 = 2 * hd - 1, w0 = 2 * wd - 1;
    #pragma unroll
    for (int jj = 0; jj < 4; ++jj) {
        int c = c0 + cg + jj;
        const float* base = x + (((size_t)(n * 256 + c) * 4 + t) << 12);
        float s = 0.f;
        #pragma unroll
        for (int dh = 0; dh < 3; ++dh) {
            int h = h0 + dh;
            if ((unsigned)h < 64u) {
                const float* row = base + h * 64;
                #pragma unroll
                for (int dw = 0; dw < 3; ++dw) {
                    int w = w0 + dw;
                    if ((unsigned)w < 64u) s += row[w];
                }
            }
        }
        P[wd][cg + jj] = us(s * (1.f / 9.f));
    }
    __syncthreads();
    int key = r * 32 + (tid >> 3);
    int cc = (tid & 7) * 4;
    uint2 w = *(const uint2*)&P[tid >> 3][cc];
    *(uint2*)(xpT + (((size_t)n << 12) + key) * 256 + c0 + cc) = w;
}

// ---------------------------------------------------------------------------
// conv_q: Q[n*16384+px][ic] = sum_c xT[px][c]*theta_w[ic][c] + theta_b[ic]
// B-fragments are single b128 loads from xT (c-contiguous).
// ---------------------------------------------------------------------------
__launch_bounds__(256)
__global__ void k_convq(const unsigned short* __restrict__ xT, const unsigned short* __restrict__ TW,
                        const float* __restrict__ tb, unsigned short* __restrict__ Q) {
    __shared__ unsigned short Qs[4][16][132];   // [wave][px][ic], +4 pad
    int tid = threadIdx.x, wid = tid >> 6, lane = tid & 63, quad = lane >> 4, l16 = lane & 15;
    int n = blockIdx.y;
    int px0 = blockIdx.x * 64 + wid * 16;
    const unsigned short* xb = xT + (((size_t)n << 14) + px0 + l16) * 256;
    floatx4 acc[8];
    #pragma unroll
    for (int i = 0; i < 8; ++i) acc[i] = (floatx4)0.f;
    for (int kc = 0; kc < 8; ++kc) {
        int cbase = kc * 32 + quad * 8;
        short8 b = *(const short8*)(xb + cbase);
        #pragma unroll
        for (int mt = 0; mt < 8; ++mt) {
            short8 a = *(const short8*)(TW + (mt * 16 + l16) * 256 + cbase);
            acc[mt] = MFMA16(a, b, acc[mt]);
        }
    }
    #pragma unroll
    for (int mt = 0; mt < 8; ++mt) {
        int ic = mt * 16 + quad * 4;
        uint2 w;
        w.x = pkfast(acc[mt][0] + tb[ic], acc[mt][1] + tb[ic + 1]);
        w.y = pkfast(acc[mt][2] + tb[ic + 2], acc[mt][3] + tb[ic + 3]);
        *(uint2*)&Qs[wid][l16][ic] = w;
    }
    #pragma unroll
    for (int i = 0; i < 4; ++i) {
        int pxl = i * 4 + quad;
        short8 row = *(const short8*)&Qs[wid][pxl][l16 * 8];
        *(short8*)(Q + ((((size_t)n << 14) + px0 + pxl) << 7) + l16 * 8) = row;
    }
}

// ---------------------------------------------------------------------------
// conv_kv v2: 32 keys/WG (grid 256 = full GPU). Waves 0,1: K (phi); waves 2,3:
// V (g). B-frags = b128 loads from xpT. Writes St chunk half-images (layout
// identical to R6 -> attn unchanged).
// ---------------------------------------------------------------------------
__launch_bounds__(256)
__global__ void k_convkv(const unsigned short* __restrict__ xpT,
                         const unsigned short* __restrict__ PW, const float* __restrict__ pb,
                         const unsigned short* __restrict__ GW, const float* __restrict__ gb,
                         unsigned short* __restrict__ Stg) {
    __shared__ unsigned short Ks[2][16][132];
    __shared__ unsigned short Vs[32][132];
    int tid = threadIdx.x, wid = tid >> 6, lane = tid & 63, quad = lane >> 4, l16 = lane & 15;
    int n = blockIdx.y;
    int c32 = blockIdx.x;                 // 32-key tile index
    int chunk = c32 >> 1, half = c32 & 1;
    int k0 = c32 * 32;
    int role = wid >> 1, kg = wid & 1;    // role 0 = K(phi), 1 = V(g)
    int key = k0 + kg * 16 + l16;
    unsigned short* sc = Stg + (size_t)(n * 64 + chunk) * CHUNK_SHORTS;
    const unsigned short* xb = xpT + (((size_t)n << 12) + key) * 256;
    const unsigned short* W = role ? GW : PW;
    const float* bias = role ? gb : pb;
    floatx4 acc[8];
    #pragma unroll
    for (int i = 0; i < 8; ++i) acc[i] = (floatx4)0.f;
    for (int kc = 0; kc < 8; ++kc) {
        int cbase = kc * 32 + quad * 8;
        short8 b = *(const short8*)(xb + cbase);
        #pragma unroll
        for (int mt = 0; mt < 8; ++mt) {
            short8 a = *(const short8*)(W + (mt * 16 + l16) * 256 + cbase);
            acc[mt] = MFMA16(a, b, acc[mt]);
        }
    }
    int hd = (key >> 5) & 31, wdd = key & 31;
    float frac = ((hd == 0) ? 2.f : 3.f) * ((wdd == 0) ? 2.f : 3.f) * (1.f / 9.f);

    if (role == 0) {
        // K epilogue: per-wave transpose, coalesced b128 stores into St K rows
        #pragma unroll
        for (int mt = 0; mt < 8; ++mt) {
            int ic = mt * 16 + quad * 4;
            uint2 w;
            w.x = pkfast(acc[mt][0] + bias[ic] * frac, acc[mt][1] + bias[ic + 1] * frac);
            w.y = pkfast(acc[mt][2] + bias[ic + 2] * frac, acc[mt][3] + bias[ic + 3] * frac);
            *(uint2*)&Ks[kg][l16][ic] = w;
        }
        #pragma unroll
        for (int i = 0; i < 4; ++i) {
            int pxl = i * 4 + quad;
            short8 row = *(const short8*)&Ks[kg][pxl][l16 * 8];
            *(short8*)(sc + (half * 32 + kg * 16 + pxl) * 136 + l16 * 8) = row;
        }
    } else {
        // V: write C-tile to WG-shared [key][ic] buffer
        #pragma unroll
        for (int mt = 0; mt < 8; ++mt) {
            int ic = mt * 16 + quad * 4;
            uint2 w;
            w.x = pkfast(acc[mt][0] + bias[ic] * frac, acc[mt][1] + bias[ic + 1] * frac);
            w.y = pkfast(acc[mt][2] + bias[ic + 2] * frac, acc[mt][3] + bias[ic + 3] * frac);
            *(uint2*)&Vs[kg * 16 + l16][ic] = w;
        }
    }
    __syncthreads();
    // V transpose-write: 128 ic rows x 32 keys -> St V half-rows (b128)
    #pragma unroll
    for (int it2 = 0; it2 < 2; ++it2) {
        int ic = it2 * 64 + (tid >> 2);
        int kk = (tid & 3) * 8;
        uint4v w;
        #pragma unroll
        for (int j = 0; j < 4; ++j) {
            unsigned s0 = Vs[kk + 2 * j][ic];
            unsigned s1 = Vs[kk + 2 * j + 1][ic];
            w[j] = s0 | (s1 << 16);
        }
        *(uint4v*)(sc + VOFF_SHORTS + ic * 72 + half * 32 + kk) = w;
    }
    // grid channels (128..130) and zero rows (131..159): 32 rows x 32 keys
    #pragma unroll
    for (int it = 0; it < 4; ++it) {
        int e = it * 256 + tid;
        int row = 128 + (e >> 5);
        int kl = e & 31;
        int kk = k0 + kl;
        int t = kk >> 10, hh = (kk >> 5) & 31, ww = kk & 31;
        unsigned short v = 0;
        if (row == 128) v = f2bf(((float)t * (1.f / 1.5f) - 1.f) * 0.1f);
        else if (row == 129) v = f2bf((float)hh * (1.f / 15.5f) - 1.f);
        else if (row == 130) v = f2bf((float)ww * (1.f / 7.75f) - 2.f);
        sc[VOFF_SHORTS + row * 72 + half * 32 + kl] = v;
    }
}

// ---------------------------------------------------------------------------
// softmax + PV for one 32-key subtile (in-register P transpose)
// ---------------------------------------------------------------------------
__device__ __forceinline__ void softmax_pv(const floatx16 st, int ks,
                                           const short (*Vlds)[72], floatx16* O,
                                           float& lacc, int l32, int half) {
    unsigned u[8];
    #pragma unroll
    for (int a = 0; a < 4; ++a) {
        float p0 = exp2f(fmaf(st[4 * a + 0], 1.44269504f, -17.3123404907f));
        float p1 = exp2f(fmaf(st[4 * a + 1], 1.44269504f, -17.3123404907f));
        float p2 = exp2f(fmaf(st[4 * a + 2], 1.44269504f, -17.3123404907f));
        float p3 = exp2f(fmaf(st[4 * a + 3], 1.44269504f, -17.3123404907f));
        lacc += (p0 + p1) + (p2 + p3);
        u[2 * a] = pkfast(p0, p1);
        u[2 * a + 1] = pkfast(p2, p3);
    }
    unsigned xu[8];
    #pragma unroll
    for (int g = 0; g < 8; ++g) xu[g] = (unsigned)__shfl_xor((int)u[g], 32);
    uint4v pw0, pw1;
    pw0[0] = half ? xu[2] : u[0];
    pw0[1] = half ? xu[3] : u[1];
    pw0[2] = half ? u[2] : xu[0];
    pw0[3] = half ? u[3] : xu[1];
    pw1[0] = half ? xu[6] : u[4];
    pw1[1] = half ? xu[7] : u[5];
    pw1[2] = half ? u[6] : xu[4];
    pw1[3] = half ? u[7] : xu[5];
    short8 pf0 = __builtin_bit_cast(short8, pw0);
    short8 pf1 = __builtin_bit_cast(short8, pw1);
    #pragma unroll
    for (int vt = 0; vt < 5; ++vt) {
        short8 vf0 = *(const short8*)&Vlds[vt * 32 + l32][ks * 32 + half * 8];
        O[vt] = MFMA32(vf0, pf0, O[vt]);
        short8 vf1 = *(const short8*)&Vlds[vt * 32 + l32][ks * 32 + 16 + half * 8];
        O[vt] = MFMA32(vf1, pf1, O[vt]);
    }
}

// ---------------------------------------------------------------------------
// flash attention v6: global_load_lds staging, split-K=3, launch_bounds(256,3)
// ---------------------------------------------------------------------------
__launch_bounds__(256, 3)
__global__ void k_attn(const unsigned short* __restrict__ Q,
                       const unsigned char* __restrict__ Stg,
                       unsigned short* __restrict__ Y, float* __restrict__ L) {
    __shared__ __align__(16) char Sh[CHUNK_BYTES];
    int tid = threadIdx.x, wid = tid >> 6, lane = tid & 63;
    int l32 = lane & 31, half = lane >> 5;
    int n = blockIdx.y, sp = blockIdx.z;
    int c0 = (sp * 64) / SPLITS, c1 = ((sp + 1) * 64) / SPLITS;
    int nch = c1 - c0;
    int q0 = blockIdx.x * 128 + wid * 32;

    const unsigned short* Qr = Q + ((((size_t)n << 14) + q0 + l32) << 7);
    short8 qf[8];
    #pragma unroll
    for (int kc = 0; kc < 8; ++kc) qf[kc] = *(const short8*)(Qr + kc * 16 + half * 8);

    floatx16 O[5];
    #pragma unroll
    for (int t = 0; t < 5; ++t) O[t] = (floatx16)0.f;
    float lacc = 0.f;

    const short (*Klds)[136] = (const short(*)[136])Sh;
    const short (*Vlds)[72] = (const short(*)[72])(Sh + 17408);

    const unsigned char* gsl = Stg + ((size_t)(n * 64 + c0)) * CHUNK_BYTES
                               + (wid * 10) * 1024 + lane * 16;
    char* lsl = Sh + (wid * 10) * 1024;

    for (int it = 0; it < nch; ++it) {
        __syncthreads();
        const unsigned char* g = gsl + (size_t)it * CHUNK_BYTES;
        #pragma unroll
        for (int i = 0; i < 10; ++i)
            gload_lds16(g + i * 1024, lsl + i * 1024);
        asm volatile("s_waitcnt vmcnt(0)" ::: "memory");
        __syncthreads();

        #pragma unroll
        for (int ks = 0; ks < 2; ++ks) {
            floatx16 st = (floatx16)0.f;
            #pragma unroll
            for (int kc = 0; kc < 8; ++kc) {
                short8 kf = *(const short8*)&Klds[ks * 32 + l32][kc * 16 + half * 8];
                st = MFMA32(kf, qf[kc], st);
            }
            softmax_pv(st, ks, Vlds, O, lacc, l32, half);
        }
    }
    float lt = lacc + __shfl_xor(lacc, 32);
    int slab = sp * 2 + n;
    unsigned short* Yb = Y + ((((size_t)slab << 14) + q0 + l32) * 160);
    #pragma unroll
    for (int vt = 0; vt < 5; ++vt)
        #pragma unroll
        for (int g = 0; g < 4; ++g) {
            int vd = vt * 32 + 8 * g + 4 * half;
            uint2 w;
            w.x = pkfast(O[vt][4 * g], O[vt][4 * g + 1]);
            w.y = pkfast(O[vt][4 * g + 2], O[vt][4 * g + 3]);
            *(uint2*)(Yb + vd) = w;
        }
    if (lane < 32) L[(((size_t)slab) << 14) + q0 + lane] = lt;
}

// ---------------------------------------------------------------------------
// final conv + split combine + normalize
// ---------------------------------------------------------------------------
__launch_bounds__(256)
__global__ void k_convf(const unsigned short* __restrict__ Y, const float* __restrict__ L,
                        const unsigned short* __restrict__ Wp, const float* __restrict__ Wb,
                        float* __restrict__ out) {
    int tid = threadIdx.x, wid = tid >> 6, lane = tid & 63, quad = lane >> 4, l16 = lane & 15;
    int n = blockIdx.y;
    int p0 = blockIdx.x * 64;
    floatx4 acc[4][4];
    #pragma unroll
    for (int i = 0; i < 4; ++i)
        #pragma unroll
        for (int j = 0; j < 4; ++j) acc[i][j] = (floatx4)0.f;
    for (int kc = 0; kc < 5; ++kc) {
        int cb = kc * 32 + quad * 8;
        short8 a[4];
        #pragma unroll
        for (int mt = 0; mt < 4; ++mt)
            a[mt] = *(const short8*)(Wp + (size_t)(wid * 64 + mt * 16 + l16) * 160 + cb);
        #pragma unroll
        for (int sp = 0; sp < SPLITS; ++sp) {
            const unsigned short* Yb = Y + ((((size_t)(sp * 2 + n)) << 14) + p0) * 160;
            #pragma unroll
            for (int nt = 0; nt < 4; ++nt) {
                short8 b = *(const short8*)(Yb + (size_t)(nt * 16 + l16) * 160 + cb);
                #pragma unroll
                for (int mt = 0; mt < 4; ++mt) acc[mt][nt] = MFMA16(a[mt], b, acc[mt][nt]);
            }
        }
    }
    float linv[4];
    #pragma unroll
    for (int nt = 0; nt < 4; ++nt) {
        int p = p0 + nt * 16 + l16;
        float ls = 0.f;
        #pragma unroll
        for (int sp = 0; sp < SPLITS; ++sp) ls += L[(((size_t)(sp * 2 + n)) << 14) + p];
        linv[nt] = 1.f / ls;
    }
    #pragma unroll
    for (int mt = 0; mt < 4; ++mt)
        #pragma unroll
        for (int r = 0; r < 4; ++r) {
            int oc = wid * 64 + mt * 16 + quad * 4 + r;
            float bb = Wb[oc];
            float* orow = out + ((((size_t)n << 8) + oc) << 14) + p0;
            #pragma unroll
            for (int nt = 0; nt < 4; ++nt)
                orow[nt * 16 + l16] = acc[mt][nt][r] * linv[nt] + bb;
        }
}

// ---------------------------------------------------------------------------
extern "C" void kernel_launch(void* const* d_in, const int* in_sizes, int n_in,
                              void* d_out, int out_size, void* d_ws, size_t ws_size,
                              hipStream_t stream) {
    (void)in_sizes; (void)n_in; (void)out_size; (void)ws_size;
    const float* x   = (const float*)d_in[0];
    const float* thw = (const float*)d_in[1];
    const float* thb = (const float*)d_in[2];
    const float* phw = (const float*)d_in[3];
    const float* phb = (const float*)d_in[4];
    const float* gw_ = (const float*)d_in[5];
    const float* gb_ = (const float*)d_in[6];
    const float* Ww  = (const float*)d_in[7];
    const float* Wb  = (const float*)d_in[8];
    float* out = (float*)d_out;

    char* ws = (char*)d_ws;
    size_t off = 0;
    auto alloc = [&](size_t b) { size_t o = off; off += (b + 255) & ~(size_t)255; return o; };
    unsigned short* TW = (unsigned short*)(ws + alloc(32768 * 2));
    unsigned short* PW = (unsigned short*)(ws + alloc(32768 * 2));
    unsigned short* GW = (unsigned short*)(ws + alloc(32768 * 2));
    unsigned short* Wp = (unsigned short*)(ws + alloc(40960 * 2));
    unsigned short* Qb = (unsigned short*)(ws + alloc((size_t)32768 * 128 * 2));
    unsigned short* St = (unsigned short*)(ws + alloc((size_t)2 * 64 * CHUNK_BYTES));
    float*          Lb = (float*)(ws + alloc((size_t)SPLITS * 2 * 16384 * 4));
    // Y: [split*2+n][p][160]. xT (16.8 MB) + xpT (4.2 MB) alias into Y's region:
    // both are dead before attn writes Y (same-stream ordering), convf reads Y last.
    size_t ybytes = (size_t)SPLITS * 2 * 16384 * 160 * 2;
    unsigned short* Yb  = (unsigned short*)(ws + alloc(ybytes));
    unsigned short* xT  = Yb;
    unsigned short* xpT = (unsigned short*)((char*)Yb + (size_t)2 * 16384 * 256 * 2);

    k_prep<<<(139264 + 255) / 256, 256, 0, stream>>>(thw, phw, gw_, Ww, TW, PW, GW, Wp);
    k_xt<<<dim3(2048, 2), 256, 0, stream>>>(x, xT);
    k_poolT<<<dim3(1024, 2), 256, 0, stream>>>(x, xpT);
    k_convq<<<dim3(256, 2), 256, 0, stream>>>(xT, TW, thb, Qb);
    k_convkv<<<dim3(128, 2), 256, 0, stream>>>(xpT, PW, phb, GW, gb_, St);
    k_attn<<<dim3(128, 2, SPLITS), 256, 0, stream>>>(Qb, (const unsigned char*)St, Yb, Lb);
    k_convf<<<dim3(256, 2), 256, 0, stream>>>(Yb, Lb, Wp, Wb, out);
}